// Round 7
// baseline (103.828 us; speedup 1.0000x reference)
//
#include <hip/hip_runtime.h>
#include <hip/hip_bf16.h>

// Spatial Transformer: B=256, C=32, H=W=64. All fp32 in/out.
//   k1: bf16 MFMA k-split GEMM via global_load_lds staging of x (VGPR-bypass, deep in-flight),
//       source-side XOR swizzle (g ^= row&7 per 16B granule) + same XOR on ds_read_b128 ->
//       full 32-bank spread. w staged once as bf16 MFMA frags. partial[256->][kc][j] fp32.
//   k2: reduce partials (contiguous stream) + bias/relu + layer2 + layer3 -> theta[256,8]
//   k3: affine grid + bilinear sample (all but last 2048 elems)
//   k3tail: last 2048 elems (overlap theta storage; read-then-write)

#define K_TOT 131072
#define KC    256           // k per block
#define KSPL  (K_TOT/KC)    // 512 k-chunks; partial layout [b][kc][j]

typedef short s16x8 __attribute__((ext_vector_type(8)));   // 8 bf16 in 4 VGPRs
typedef float f32x4 __attribute__((ext_vector_type(4)));

__device__ __forceinline__ short f2bf(float f) {
    return __builtin_bit_cast(short, __float2bfloat16(f));  // RNE scalar; fuses to cvt_pk
}

__device__ __forceinline__ s16x8 cvt8(float4 a, float4 b) {
    s16x8 r;
    r[0] = f2bf(a.x); r[1] = f2bf(a.y); r[2] = f2bf(a.z); r[3] = f2bf(a.w);
    r[4] = f2bf(b.x); r[5] = f2bf(b.y); r[6] = f2bf(b.z); r[7] = f2bf(b.w);
    return r;
}

__device__ __forceinline__ void gload_lds16(const float* g, float* l) {
    __builtin_amdgcn_global_load_lds(
        (const __attribute__((address_space(1))) void*)(g),
        (__attribute__((address_space(3))) void*)(l),
        16, 0, 0);   // dwordx4 direct-to-LDS; dest = wave-uniform base + lane*16
}

__global__ __launch_bounds__(256) void st_lin1(const float* __restrict__ x,
                                               const float* __restrict__ w1,
                                               float* __restrict__ partial) {
    // Block: 32 batch rows (bg) x KC=256 k (kc). grid 4096 = 512 kc x 8 bg.
    // XCD swizzle: contiguous kc range per XCD -> per-XCD w working set 2 MB (L2-resident).
    const int bid = blockIdx.x;             // 0..4095
    const int xcd = bid & 7;
    const int s8  = bid >> 3;               // 0..511
    const int kc  = xcd * 64 + (s8 >> 3);   // 0..511
    const int bg  = s8 & 7;                 // 0..7

    const int t    = threadIdx.x;
    const int wv   = t >> 6;                // wave 0..3: rh = wv&1 (row half), jh = wv>>1 (j half)
    const int lane = t & 63;
    const int m    = lane & 15;             // A: row within 16-tile; B: col (j)
    const int kb   = lane >> 4;             // k-block 0..3 (8 k each)
    const int rh   = wv & 1;
    const int jh   = wv >> 1;

    const int b0 = bg * 32;
    const size_t k0 = (size_t)kc * KC;

    __shared__ float xbuf[32 * KC];                 // 32 KB fp32, row-major [32][256], swizzled granules
    __shared__ s16x8 wlds[(KC / 32) * 2 * 64];      // 16 KB bf16 frags: [ss][jh][lane]

    // ---- issue x DMA: 32 instrs block-wide, one row each; 1 KB contiguous global per instr.
    // LDS linear; source granule pre-swizzled: LDS[r][g] <- x[b0+r][(g ^ (r&7)) quad]
#pragma unroll
    for (int i = 0; i < 8; ++i) {
        const int r = wv * 8 + i;                   // row 0..31 (wave-uniform)
        const float* gsrc = x + (size_t)(b0 + r) * K_TOT + k0 + ((lane ^ (r & 7)) << 2);
        gload_lds16(gsrc, &xbuf[r * KC]);
    }

    // ---- stage w slice [32 j][KC] as bf16 frags (reg path; overlaps x DMA)
#pragma unroll
    for (int i = 0; i < 4; ++i) {
        const int f  = i * 256 + t;                 // 0..1023
        const int fm = f & 15;
        const int fk = (f >> 4) & 3;
        const int fj = (f >> 6) & 1;
        const int fs = f >> 7;                      // 0..7
        const float* wp = w1 + (size_t)(fj * 16 + fm) * K_TOT + k0 + fs * 32 + fk * 8;
        const float4 wa = *(const float4*)(wp);
        const float4 wb = *(const float4*)(wp + 4);
        wlds[f] = cvt8(wa, wb);
    }

    __syncthreads();   // drains DMA (vmcnt) + w ds_writes

    f32x4 acc = {0.f, 0.f, 0.f, 0.f};
    const int row = rh * 16 + m;                    // LDS row this lane reads
    const int sw  = m & 7;                          // read-side XOR (matches r&7 at stage)
    const float* xr = &xbuf[row * KC];

#pragma unroll
    for (int ss = 0; ss < KC / 32; ++ss) {
        const int gb = ss * 8 + kb * 2;             // granule of k = ss*32 + kb*8
        const float4 fa = *(const float4*)(xr + ((gb ^ sw) << 2));
        const float4 fb = *(const float4*)(xr + (((gb + 1) ^ sw) << 2));
        const s16x8 af = cvt8(fa, fb);
        const s16x8 bf = wlds[(ss * 2 + jh) * 64 + lane];
        acc = __builtin_amdgcn_mfma_f32_16x16x32_bf16(af, bf, acc, 0, 0, 0);
    }

    // C/D: col(j) = m, row(b within 16-tile) = kb*4 + rr. partial[b][kc][j], strideB = KSPL*32.
    const size_t strideB = (size_t)KSPL * 32;
    float* p0 = partial + (size_t)(b0 + rh * 16 + kb * 4) * strideB + (size_t)kc * 32 + jh * 16 + m;
#pragma unroll
    for (int rr = 0; rr < 4; ++rr)
        p0[(size_t)rr * strideB] = acc[rr];
}

__global__ __launch_bounds__(256) void st_mlp(const float* __restrict__ partial,
                                              const float* __restrict__ b1,
                                              const float* __restrict__ w2,
                                              const float* __restrict__ b2,
                                              const float* __restrict__ w3,
                                              const float* __restrict__ b3,
                                              float* __restrict__ theta) {
    const int b = blockIdx.x;
    const int t = threadIdx.x;
    const float* pb = partial + (size_t)b * KSPL * 32;   // 64 KB contiguous per block

    // Coalesced stream; thread t's j-quad class is constant: (4t)&31 (1024 % 32 == 0).
    float4 v = {0.f, 0.f, 0.f, 0.f};
#pragma unroll
    for (int i = 0; i < KSPL * 32 / 1024; ++i) {
        const float4 u = *(const float4*)(pb + (size_t)(i * 256 + t) * 4);
        v.x += u.x; v.y += u.y; v.z += u.z; v.w += u.w;
    }

    __shared__ float4 ld[256];
    __shared__ float s1s[32];
    __shared__ float s2s[32];
    ld[t] = v;
    __syncthreads();
    // Tree-reduce with offsets multiple of 8 -> merges only same j-quad classes.
#pragma unroll
    for (int off = 128; off >= 8; off >>= 1) {
        if (t < off) {
            float4 a = ld[t];
            const float4 c = ld[t + off];
            a.x += c.x; a.y += c.y; a.z += c.z; a.w += c.w;
            ld[t] = a;
        }
        __syncthreads();
    }
    if (t < 8) {   // thread t holds j-quad 4t..4t+3
        const float4 q = ld[t];
        s1s[4 * t + 0] = fmaxf(q.x + b1[4 * t + 0], 0.f);
        s1s[4 * t + 1] = fmaxf(q.y + b1[4 * t + 1], 0.f);
        s1s[4 * t + 2] = fmaxf(q.z + b1[4 * t + 2], 0.f);
        s1s[4 * t + 3] = fmaxf(q.w + b1[4 * t + 3], 0.f);
    }
    __syncthreads();
    if (t < 32) {
        float vv = b2[t];
#pragma unroll
        for (int i = 0; i < 32; ++i) vv += w2[t * 32 + i] * s1s[i];
        s2s[t] = fmaxf(vv, 0.f);
    }
    __syncthreads();
    if (t < 8) {
        float vv = 0.f;
        if (t < 6) {
            vv = b3[t];
#pragma unroll
            for (int i = 0; i < 32; ++i) vv += w3[t * 32 + i] * s2s[i];
        }
        theta[b * 8 + t] = vv;
    }
}

__device__ __forceinline__ void sample_one(int h, int w,
                                           float t0, float t1, float t2,
                                           float t3, float t4, float t5,
                                           float& wgt00, float& wgt10, float& wgt01, float& wgt11,
                                           int& cy0, int& cy1, int& cx0, int& cx1) {
    const float xs = ((float)w - 31.5f) * 0.03125f;
    const float ys = ((float)h - 31.5f) * 0.03125f;
    const float gxn = fmaf(t1, ys, fmaf(t0, xs, t2));
    const float gyn = fmaf(t4, ys, fmaf(t3, xs, t5));
    const float gx = fmaf(gxn, 32.f, 31.5f);
    const float gy = fmaf(gyn, 32.f, 31.5f);
    const float x0f = floorf(gx), y0f = floorf(gy);
    const float wx1 = gx - x0f, wx0 = 1.f - wx1;
    const float wy1 = gy - y0f, wy0 = 1.f - wy1;
    const int ix = (int)x0f, iy = (int)y0f;
    const bool vx0 = (ix >= 0) && (ix < 64);
    const bool vx1 = (ix >= -1) && (ix < 63);
    const bool vy0 = (iy >= 0) && (iy < 64);
    const bool vy1 = (iy >= -1) && (iy < 63);
    cx0 = min(max(ix, 0), 63);
    cx1 = min(max(ix + 1, 0), 63);
    cy0 = min(max(iy, 0), 63);
    cy1 = min(max(iy + 1, 0), 63);
    wgt00 = wx0 * wy0 * ((vx0 && vy0) ? 1.f : 0.f);
    wgt10 = wx1 * wy0 * ((vx1 && vy0) ? 1.f : 0.f);
    wgt01 = wx0 * wy1 * ((vx0 && vy1) ? 1.f : 0.f);
    wgt11 = wx1 * wy1 * ((vx1 && vy1) ? 1.f : 0.f);
}

__global__ __launch_bounds__(256) void st_sample(const float* __restrict__ x,
                                                 const float* theta,
                                                 float* out) {
    const int bid = blockIdx.x;
    const int b = bid >> 6;
    const int h = bid & 63;
    const int t = threadIdx.x;
    const int w = t & 63;
    const int c0 = t >> 6;

    const float* tb = theta + b * 8;
    const float t0 = tb[0], t1 = tb[1], t2 = tb[2];
    const float t3 = tb[3], t4 = tb[4], t5 = tb[5];

    float w00, w10, w01, w11;
    int cy0, cy1, cx0, cx1;
    sample_one(h, w, t0, t1, t2, t3, t4, t5, w00, w10, w01, w11, cy0, cy1, cx0, cx1);

    const bool tailblk = (b == 255) && (h >= 32);
    const int r0 = cy0 * 64, r1 = cy1 * 64;

#pragma unroll
    for (int i = 0; i < 8; ++i) {
        const int c = c0 + 4 * i;
        const float* img = x + (((size_t)b * 32 + c) << 12);
        const float v = w00 * img[r0 + cx0] + w10 * img[r0 + cx1]
                      + w01 * img[r1 + cx0] + w11 * img[r1 + cx1];
        if (!(tailblk && c == 31)) {
            __builtin_nontemporal_store(v, &out[(((size_t)b * 32 + c) << 12) + h * 64 + w]);
        }
    }
}

// Last 2048 elements: b=255, c=31, h in [32,64). This region of d_out holds theta:
// read theta first, sync, then overwrite.
__global__ __launch_bounds__(256) void st_sample_tail(const float* __restrict__ x,
                                                      float* out,
                                                      long long tailstart) {
    const float* tb = out + tailstart + 255 * 8;
    const float t0 = tb[0], t1 = tb[1], t2 = tb[2];
    const float t3 = tb[3], t4 = tb[4], t5 = tb[5];

    const int t = threadIdx.x;
    float vals[8];
#pragma unroll
    for (int i = 0; i < 8; ++i) {
        const long long e = tailstart + (long long)i * 256 + t;
        const int w = (int)(e & 63);
        const int h = (int)((e >> 6) & 63);
        const int c = (int)((e >> 12) & 31);
        const int b = (int)(e >> 17);
        float w00, w10, w01, w11;
        int cy0, cy1, cx0, cx1;
        sample_one(h, w, t0, t1, t2, t3, t4, t5, w00, w10, w01, w11, cy0, cy1, cx0, cx1);
        const float* img = x + (((size_t)b * 32 + c) << 12);
        vals[i] = w00 * img[cy0 * 64 + cx0] + w10 * img[cy0 * 64 + cx1]
                + w01 * img[cy1 * 64 + cx0] + w11 * img[cy1 * 64 + cx1];
    }
    __syncthreads();
#pragma unroll
    for (int i = 0; i < 8; ++i) {
        const long long e = tailstart + (long long)i * 256 + t;
        out[e] = vals[i];
    }
}

extern "C" void kernel_launch(void* const* d_in, const int* in_sizes, int n_in,
                              void* d_out, int out_size, void* d_ws, size_t ws_size,
                              hipStream_t stream) {
    const float* x  = (const float*)d_in[0];
    const float* w1 = (const float*)d_in[1];
    const float* b1 = (const float*)d_in[2];
    const float* w2 = (const float*)d_in[3];
    const float* b2 = (const float*)d_in[4];
    const float* w3 = (const float*)d_in[5];
    const float* b3 = (const float*)d_in[6];
    float* out = (float*)d_out;

    const long long tailstart = (long long)out_size - 2048;
    float* partial = out;                   // [256][512][32] = 16.8 MB, overwritten by st_sample
    float* theta   = out + tailstart;       // [256][8] in the tail 2048

    st_lin1<<<4096, 256, 0, stream>>>(x, w1, partial);
    st_mlp<<<256, 256, 0, stream>>>(partial, b1, w2, b2, w3, b3, theta);
    st_sample<<<256 * 64, 256, 0, stream>>>(x, theta, out);
    st_sample_tail<<<1, 256, 0, stream>>>(x, out, tailstart);
}

// Round 9
// 96.265 us; speedup vs baseline: 1.0786x; 1.0786x over previous
//
#include <hip/hip_runtime.h>
#include <hip/hip_bf16.h>
#include <hip/hip_cooperative_groups.h>

namespace cg = cooperative_groups;

// Spatial Transformer: B=256, C=32, H=W=64. All fp32 in/out.
// Three phases (one cooperative kernel when co-residency allows, else 3 kernels):
//   P1 (512 blocks): bf16 MFMA GEMM x[256,131072] @ w1^T -> partial[256][1024][32] in d_ws.
//       Block owns kc (w frags staged to LDS ONCE, amortized over 16 tiles); 8 tiles of
//       32 batch rows via global_load_lds DMA (32 KB in flight), XOR-swizzled source.
//   P2 (256 blocks): reduce partial (128 KB contiguous/block) + MLP -> theta[256][8] in d_ws.
//   P3 (512 blocks): affine grid + bilinear sample -> d_out (no aliasing, no tail kernel).

#define K_TOT 131072
#define KC    256
#define PKN   1024                      // partial k-slots = 512 kc * 2 k-halves
#define STRB  ((size_t)PKN * 32)        // floats per batch row of partial

typedef short s16x8 __attribute__((ext_vector_type(8)));   // 8 bf16 in 4 VGPRs
typedef float f32x4 __attribute__((ext_vector_type(4)));

__device__ __forceinline__ short f2bf(float f) {
    return __builtin_bit_cast(short, __float2bfloat16(f));  // RNE; fuses to cvt_pk
}

__device__ __forceinline__ s16x8 cvt8(float4 a, float4 b) {
    s16x8 r;
    r[0] = f2bf(a.x); r[1] = f2bf(a.y); r[2] = f2bf(a.z); r[3] = f2bf(a.w);
    r[4] = f2bf(b.x); r[5] = f2bf(b.y); r[6] = f2bf(b.z); r[7] = f2bf(b.w);
    return r;
}

__device__ __forceinline__ void gload_lds16(const float* g, float* l) {
    __builtin_amdgcn_global_load_lds(
        (const __attribute__((address_space(1))) void*)(g),
        (__attribute__((address_space(3))) void*)(l),
        16, 0, 0);   // dwordx4 direct-to-LDS; dest = wave-uniform base + lane*16
}

// ===================== P1 =====================
__device__ __forceinline__ void phase1(int bid, const float* __restrict__ x,
                                       const float* __restrict__ w1,
                                       float* __restrict__ partial, char* smem) {
    float* xbuf = (float*)smem;                 // [32][256] fp32 (32 KB), swizzled granules
    s16x8* wlds = (s16x8*)(smem + 32768);       // 1024 bf16 frags (16 KB)

    const int t    = threadIdx.x;
    const int wv   = t >> 6;
    const int lane = t & 63;
    const int m    = lane & 15;
    const int kb   = lane >> 4;
    const int jh   = wv & 1;                    // j half
    const int kh   = wv >> 1;                   // k half

    const int xcd = bid & 7;                    // XCD swizzle: contiguous kc per XCD
    const int kc  = xcd * 64 + (bid >> 3);      // 0..511
    const size_t k0 = (size_t)kc * KC;

    // stage w slice [32 j][256 k] as bf16 MFMA B-frags, ONCE per block
#pragma unroll
    for (int i = 0; i < 4; ++i) {
        const int f  = i * 256 + t;
        const int fm = f & 15, fk = (f >> 4) & 3, fj = (f >> 6) & 1, fs = f >> 7;
        const float* wp = w1 + (size_t)(fj * 16 + fm) * K_TOT + k0 + fs * 32 + fk * 8;
        wlds[f] = cvt8(*(const float4*)wp, *(const float4*)(wp + 4));
    }

    const int pk = kc * 2 + kh;
    for (int it = 0; it < 8; ++it) {
        const int b0 = it * 32;
        __syncthreads();                        // prev tile's readers done; wlds visible (it=0)
        // DMA 32 rows (8/wave), 1 KB contiguous global each; source granule XOR-swizzled
#pragma unroll
        for (int i2 = 0; i2 < 8; ++i2) {
            const int r = wv * 8 + i2;
            const float* gsrc = x + (size_t)(b0 + r) * K_TOT + k0 + ((lane ^ (r & 7)) << 2);
            gload_lds16(gsrc, xbuf + r * 256);
        }
        __syncthreads();                        // vmcnt(0) drain -> DMA complete + visible

#pragma unroll
        for (int sub = 0; sub < 2; ++sub) {
            const int row = sub * 16 + m;
            const float* xr = xbuf + row * 256;
            const int sw = m & 7;               // (sub*16+m)&7 == m&7
            f32x4 acc = {0.f, 0.f, 0.f, 0.f};
#pragma unroll
            for (int sss = 0; sss < 4; ++sss) {
                const int gb = kh * 32 + sss * 8 + kb * 2;     // 16B granule index of k
                const float4 fa = *(const float4*)(xr + ((gb ^ sw) << 2));
                const float4 fb = *(const float4*)(xr + (((gb + 1) ^ sw) << 2));
                const s16x8 af = cvt8(fa, fb);
                const s16x8 bf = wlds[((kh * 4 + sss) * 2 + jh) * 64 + lane];
                acc = __builtin_amdgcn_mfma_f32_16x16x32_bf16(af, bf, acc, 0, 0, 0);
            }
            // C/D: col(j)=m, row(b within 16)=kb*4+rr
            float* p0 = partial + (size_t)(b0 + sub * 16 + kb * 4) * STRB
                                + (size_t)pk * 32 + jh * 16 + m;
#pragma unroll
            for (int rr = 0; rr < 4; ++rr)
                p0[(size_t)rr * STRB] = acc[rr];
        }
    }
}

// ===================== P2 =====================
__device__ __forceinline__ void phase2(int b, const float* __restrict__ partial,
                                       const float* __restrict__ b1,
                                       const float* __restrict__ w2,
                                       const float* __restrict__ b2,
                                       const float* __restrict__ w3,
                                       const float* __restrict__ b3,
                                       float* __restrict__ theta, char* smem) {
    const int t = threadIdx.x;
    const float* pb = partial + (size_t)b * STRB;       // 128 KB contiguous

    float4 v = {0.f, 0.f, 0.f, 0.f};
#pragma unroll
    for (int i = 0; i < 32; ++i) {                      // j-class of thread t = (4t)&31
        const float4 u = *(const float4*)(pb + (size_t)(i * 256 + t) * 4);
        v.x += u.x; v.y += u.y; v.z += u.z; v.w += u.w;
    }

    float4* red = (float4*)smem;
    float*  s1s = (float*)(smem + 4096);
    float*  s2s = (float*)(smem + 4224);
    red[t] = v;
    __syncthreads();
#pragma unroll
    for (int off = 128; off >= 8; off >>= 1) {          // offsets %8==0 preserve j-class
        if (t < off) {
            float4 a = red[t];
            const float4 c = red[t + off];
            a.x += c.x; a.y += c.y; a.z += c.z; a.w += c.w;
            red[t] = a;
        }
        __syncthreads();
    }
    if (t < 8) {                                        // thread t holds j-quad 4t..4t+3
        const float4 q = red[t];
        s1s[4 * t + 0] = fmaxf(q.x + b1[4 * t + 0], 0.f);
        s1s[4 * t + 1] = fmaxf(q.y + b1[4 * t + 1], 0.f);
        s1s[4 * t + 2] = fmaxf(q.z + b1[4 * t + 2], 0.f);
        s1s[4 * t + 3] = fmaxf(q.w + b1[4 * t + 3], 0.f);
    }
    __syncthreads();
    if (t < 32) {
        float vv = b2[t];
#pragma unroll
        for (int i = 0; i < 32; ++i) vv += w2[t * 32 + i] * s1s[i];
        s2s[t] = fmaxf(vv, 0.f);
    }
    __syncthreads();
    if (t < 8) {
        float vv = 0.f;
        if (t < 6) {
            vv = b3[t];
#pragma unroll
            for (int i = 0; i < 32; ++i) vv += w3[t * 32 + i] * s2s[i];
        }
        theta[b * 8 + t] = vv;
    }
}

// ===================== P3 =====================
__device__ __forceinline__ void phase3(int bid, const float* __restrict__ x,
                                       const float* __restrict__ theta,
                                       float* __restrict__ out) {
    const int b  = bid >> 1;
    const int h0 = (bid & 1) * 32;
    const int t  = threadIdx.x;
    const int w  = t & 63;
    const int c0 = t >> 6;

    const float* tb = theta + b * 8;
    const float t0 = tb[0], t1 = tb[1], t2 = tb[2];
    const float t3 = tb[3], t4 = tb[4], t5 = tb[5];

    for (int r = 0; r < 32; ++r) {
        const int h = h0 + r;
        const float xs = ((float)w - 31.5f) * 0.03125f;
        const float ys = ((float)h - 31.5f) * 0.03125f;
        const float gxn = fmaf(t1, ys, fmaf(t0, xs, t2));
        const float gyn = fmaf(t4, ys, fmaf(t3, xs, t5));
        const float gx = fmaf(gxn, 32.f, 31.5f);
        const float gy = fmaf(gyn, 32.f, 31.5f);
        const float x0f = floorf(gx), y0f = floorf(gy);
        const float wx1 = gx - x0f, wx0 = 1.f - wx1;
        const float wy1 = gy - y0f, wy0 = 1.f - wy1;
        const int ix = (int)x0f, iy = (int)y0f;
        const bool vx0 = (ix >= 0) && (ix < 64);
        const bool vx1 = (ix >= -1) && (ix < 63);
        const bool vy0 = (iy >= 0) && (iy < 64);
        const bool vy1 = (iy >= -1) && (iy < 63);
        const int cx0 = min(max(ix, 0), 63);
        const int cx1 = min(max(ix + 1, 0), 63);
        const int cy0 = min(max(iy, 0), 63);
        const int cy1 = min(max(iy + 1, 0), 63);
        const float w00 = wx0 * wy0 * ((vx0 && vy0) ? 1.f : 0.f);
        const float w10 = wx1 * wy0 * ((vx1 && vy0) ? 1.f : 0.f);
        const float w01 = wx0 * wy1 * ((vx0 && vy1) ? 1.f : 0.f);
        const float w11 = wx1 * wy1 * ((vx1 && vy1) ? 1.f : 0.f);
        const int r0 = cy0 * 64, r1 = cy1 * 64;
#pragma unroll
        for (int i = 0; i < 8; ++i) {
            const int c = c0 + 4 * i;
            const float* img = x + (((size_t)b * 32 + c) << 12);
            const float v = w00 * img[r0 + cx0] + w10 * img[r0 + cx1]
                          + w01 * img[r1 + cx0] + w11 * img[r1 + cx1];
            __builtin_nontemporal_store(v, &out[(((size_t)b * 32 + c) << 12) + h * 64 + w]);
        }
    }
}

// ===================== kernels =====================
__global__ __launch_bounds__(256, 2) void st_coop(const float* __restrict__ x,
                                                  const float* __restrict__ w1,
                                                  const float* __restrict__ b1,
                                                  const float* __restrict__ w2,
                                                  const float* __restrict__ b2,
                                                  const float* __restrict__ w3,
                                                  const float* __restrict__ b3,
                                                  float* __restrict__ out,
                                                  float* __restrict__ ws) {
    cg::grid_group grid = cg::this_grid();
    __shared__ __align__(16) char smem[49152];
    float* partial = ws;
    float* theta   = ws + (size_t)256 * STRB;

    phase1(blockIdx.x, x, w1, partial, smem);
    grid.sync();
    if (blockIdx.x < 256)
        phase2(blockIdx.x, partial, b1, w2, b2, w3, b3, theta, smem);
    grid.sync();
    phase3(blockIdx.x, x, theta, out);
}

__global__ __launch_bounds__(256) void st_p1k(const float* __restrict__ x,
                                              const float* __restrict__ w1,
                                              float* __restrict__ partial) {
    __shared__ __align__(16) char smem[49152];
    phase1(blockIdx.x, x, w1, partial, smem);
}

__global__ __launch_bounds__(256) void st_p2k(const float* __restrict__ partial,
                                              const float* __restrict__ b1,
                                              const float* __restrict__ w2,
                                              const float* __restrict__ b2,
                                              const float* __restrict__ w3,
                                              const float* __restrict__ b3,
                                              float* __restrict__ theta) {
    __shared__ __align__(16) char smem[4352];
    phase2(blockIdx.x, partial, b1, w2, b2, w3, b3, theta, smem);
}

__global__ __launch_bounds__(256) void st_p3k(const float* __restrict__ x,
                                              const float* __restrict__ theta,
                                              float* __restrict__ out) {
    phase3(blockIdx.x, x, theta, out);
}

extern "C" void kernel_launch(void* const* d_in, const int* in_sizes, int n_in,
                              void* d_out, int out_size, void* d_ws, size_t ws_size,
                              hipStream_t stream) {
    const float* x  = (const float*)d_in[0];
    const float* w1 = (const float*)d_in[1];
    const float* b1 = (const float*)d_in[2];
    const float* w2 = (const float*)d_in[3];
    const float* b2 = (const float*)d_in[4];
    const float* w3 = (const float*)d_in[5];
    const float* b3 = (const float*)d_in[6];
    float* out = (float*)d_out;
    float* ws  = (float*)d_ws;                       // partial 33.5 MB + theta 2 KB
    float* partial = ws;
    float* theta   = ws + (size_t)256 * STRB;

    // Deterministic cooperative-capability gate (host-side queries only; no alloc/sync).
    bool launched = false;
    if (ws_size >= ((size_t)256 * STRB + 2048) * sizeof(float)) {
        int ncu = 0, nblk = 0, dev = 0;
        (void)hipGetDevice(&dev);
        (void)hipDeviceGetAttribute(&ncu, hipDeviceAttributeMultiprocessorCount, dev);
        (void)hipOccupancyMaxActiveBlocksPerMultiprocessor(&nblk, st_coop, 256, 0);
        if (ncu > 0 && nblk > 0 && (long long)nblk * ncu >= 512) {
            void* args[] = {(void*)&x, (void*)&w1, (void*)&b1, (void*)&w2, (void*)&b2,
                            (void*)&w3, (void*)&b3, (void*)&out, (void*)&ws};
            launched = (hipLaunchCooperativeKernel((void*)st_coop, dim3(512), dim3(256),
                                                   args, 0, stream) == hipSuccess);
        }
    }
    if (!launched) {
        st_p1k<<<512, 256, 0, stream>>>(x, w1, partial);
        st_p2k<<<256, 256, 0, stream>>>(partial, b1, w2, b2, w3, b3, theta);
        st_p3k<<<512, 256, 0, stream>>>(x, theta, out);
    }
}

// Round 10
// 88.188 us; speedup vs baseline: 1.1774x; 1.0916x over previous
//
#include <hip/hip_runtime.h>
#include <hip/hip_bf16.h>
#include <hip/hip_cooperative_groups.h>

namespace cg = cooperative_groups;

// Spatial Transformer: B=256, C=32, H=W=64. All fp32 in/out.
// Three phases (one cooperative kernel when co-residency allows, else 3 kernels):
//   P1 (1024 blocks, 4/CU): bf16 MFMA GEMM x[256,131072] @ w1^T -> partial[256][1024][32] (d_ws).
//       Block pair (same XCD) owns kc: w frags staged to LDS once per block (2nd is L2-hit);
//       8 tiles of 16 batch rows via global_load_lds DMA (16 KB/stage), XOR-swizzled source.
//   P2 (256 blocks): reduce partial (128 KB contiguous/block) + MLP -> theta[256][8] (d_ws).
//   P3 (1024 blocks): affine grid + bilinear sample -> d_out (16 h-rows/block).

#define K_TOT 131072
#define KC    256
#define PKN   1024                      // partial k-slots = 512 kc * 2 k-halves
#define STRB  ((size_t)PKN * 32)        // floats per batch row of partial

typedef short s16x8 __attribute__((ext_vector_type(8)));   // 8 bf16 in 4 VGPRs
typedef float f32x4 __attribute__((ext_vector_type(4)));

__device__ __forceinline__ short f2bf(float f) {
    return __builtin_bit_cast(short, __float2bfloat16(f));  // RNE; fuses to cvt_pk
}

__device__ __forceinline__ s16x8 cvt8(float4 a, float4 b) {
    s16x8 r;
    r[0] = f2bf(a.x); r[1] = f2bf(a.y); r[2] = f2bf(a.z); r[3] = f2bf(a.w);
    r[4] = f2bf(b.x); r[5] = f2bf(b.y); r[6] = f2bf(b.z); r[7] = f2bf(b.w);
    return r;
}

__device__ __forceinline__ void gload_lds16(const float* g, float* l) {
    __builtin_amdgcn_global_load_lds(
        (const __attribute__((address_space(1))) void*)(g),
        (__attribute__((address_space(3))) void*)(l),
        16, 0, 0);   // dwordx4 direct-to-LDS; dest = wave-uniform base + lane*16
}

// ===================== P1 =====================
// Block decode: xcd = bid&7, q = bid>>3 (0..127); kc = xcd*64 + (q>>1); half = q&1.
// The two halves of a kc are bids differing by 8 -> same hardware XCD -> w L2-shared.
__device__ __forceinline__ void phase1(int bid, const float* __restrict__ x,
                                       const float* __restrict__ w1,
                                       float* __restrict__ partial, char* smem) {
    float* xbuf = (float*)smem;                 // [16][256] fp32 (16 KB), swizzled granules
    s16x8* wlds = (s16x8*)(smem + 16384);       // 1024 bf16 frags (16 KB)

    const int t    = threadIdx.x;
    const int wv   = t >> 6;
    const int lane = t & 63;
    const int m    = lane & 15;
    const int kb   = lane >> 4;
    const int jh   = wv & 1;                    // j half
    const int kh   = wv >> 1;                   // k half

    const int xcd  = bid & 7;
    const int q    = bid >> 3;                  // 0..127
    const int kc   = xcd * 64 + (q >> 1);       // 0..511, contiguous per XCD
    const int half = q & 1;                     // batch half (128 rows)
    const size_t k0 = (size_t)kc * KC;

    // stage w slice [32 j][256 k] as bf16 MFMA B-frags, once per block
#pragma unroll
    for (int i = 0; i < 4; ++i) {
        const int f  = i * 256 + t;
        const int fm = f & 15, fk = (f >> 4) & 3, fj = (f >> 6) & 1, fs = f >> 7;
        const float* wp = w1 + (size_t)(fj * 16 + fm) * K_TOT + k0 + fs * 32 + fk * 8;
        wlds[f] = cvt8(*(const float4*)wp, *(const float4*)(wp + 4));
    }

    const int pk = kc * 2 + kh;
    for (int it = 0; it < 8; ++it) {
        const int b0 = half * 128 + it * 16;
        __syncthreads();                        // prev tile's readers done; wlds visible (it=0)
        // DMA 16 rows (4/wave), 1 KB contiguous global each; source granule XOR-swizzled
#pragma unroll
        for (int i2 = 0; i2 < 4; ++i2) {
            const int r = wv * 4 + i2;
            const float* gsrc = x + (size_t)(b0 + r) * K_TOT + k0 + ((lane ^ (r & 7)) << 2);
            gload_lds16(gsrc, xbuf + r * 256);
        }
        __syncthreads();                        // vmcnt(0) drain -> DMA complete + visible

        const float* xr = xbuf + m * 256;
        const int sw = m & 7;
        f32x4 acc = {0.f, 0.f, 0.f, 0.f};
#pragma unroll
        for (int sss = 0; sss < 4; ++sss) {
            const int gb = kh * 32 + sss * 8 + kb * 2;     // 16B granule index of k
            const float4 fa = *(const float4*)(xr + ((gb ^ sw) << 2));
            const float4 fb = *(const float4*)(xr + (((gb + 1) ^ sw) << 2));
            const s16x8 af = cvt8(fa, fb);
            const s16x8 bf = wlds[((kh * 4 + sss) * 2 + jh) * 64 + lane];
            acc = __builtin_amdgcn_mfma_f32_16x16x32_bf16(af, bf, acc, 0, 0, 0);
        }
        // C/D: col(j)=m, row(b within 16)=kb*4+rr
        float* p0 = partial + (size_t)(b0 + kb * 4) * STRB + (size_t)pk * 32 + jh * 16 + m;
#pragma unroll
        for (int rr = 0; rr < 4; ++rr)
            p0[(size_t)rr * STRB] = acc[rr];
    }
}

// ===================== P2 =====================
__device__ __forceinline__ void phase2(int b, const float* __restrict__ partial,
                                       const float* __restrict__ b1,
                                       const float* __restrict__ w2,
                                       const float* __restrict__ b2,
                                       const float* __restrict__ w3,
                                       const float* __restrict__ b3,
                                       float* __restrict__ theta, char* smem) {
    const int t = threadIdx.x;
    const float* pb = partial + (size_t)b * STRB;       // 128 KB contiguous

    float4 v = {0.f, 0.f, 0.f, 0.f};
#pragma unroll
    for (int i = 0; i < 32; ++i) {                      // j-class of thread t = (4t)&31
        const float4 u = *(const float4*)(pb + (size_t)(i * 256 + t) * 4);
        v.x += u.x; v.y += u.y; v.z += u.z; v.w += u.w;
    }

    float4* red = (float4*)smem;
    float*  s1s = (float*)(smem + 4096);
    float*  s2s = (float*)(smem + 4224);
    red[t] = v;
    __syncthreads();
#pragma unroll
    for (int off = 128; off >= 8; off >>= 1) {          // offsets %8==0 preserve j-class
        if (t < off) {
            float4 a = red[t];
            const float4 c = red[t + off];
            a.x += c.x; a.y += c.y; a.z += c.z; a.w += c.w;
            red[t] = a;
        }
        __syncthreads();
    }
    if (t < 8) {                                        // thread t holds j-quad 4t..4t+3
        const float4 qd = red[t];
        s1s[4 * t + 0] = fmaxf(qd.x + b1[4 * t + 0], 0.f);
        s1s[4 * t + 1] = fmaxf(qd.y + b1[4 * t + 1], 0.f);
        s1s[4 * t + 2] = fmaxf(qd.z + b1[4 * t + 2], 0.f);
        s1s[4 * t + 3] = fmaxf(qd.w + b1[4 * t + 3], 0.f);
    }
    __syncthreads();
    if (t < 32) {
        float vv = b2[t];
#pragma unroll
        for (int i = 0; i < 32; ++i) vv += w2[t * 32 + i] * s1s[i];
        s2s[t] = fmaxf(vv, 0.f);
    }
    __syncthreads();
    if (t < 8) {
        float vv = 0.f;
        if (t < 6) {
            vv = b3[t];
#pragma unroll
            for (int i = 0; i < 32; ++i) vv += w3[t * 32 + i] * s2s[i];
        }
        theta[b * 8 + t] = vv;
    }
}

// ===================== P3 =====================
__device__ __forceinline__ void phase3(int bid, const float* __restrict__ x,
                                       const float* __restrict__ theta,
                                       float* __restrict__ out) {
    const int b  = bid >> 2;
    const int h0 = (bid & 3) * 16;
    const int t  = threadIdx.x;
    const int w  = t & 63;
    const int c0 = t >> 6;

    const float* tb = theta + b * 8;
    const float t0 = tb[0], t1 = tb[1], t2 = tb[2];
    const float t3 = tb[3], t4 = tb[4], t5 = tb[5];

    for (int r = 0; r < 16; ++r) {
        const int h = h0 + r;
        const float xs = ((float)w - 31.5f) * 0.03125f;
        const float ys = ((float)h - 31.5f) * 0.03125f;
        const float gxn = fmaf(t1, ys, fmaf(t0, xs, t2));
        const float gyn = fmaf(t4, ys, fmaf(t3, xs, t5));
        const float gx = fmaf(gxn, 32.f, 31.5f);
        const float gy = fmaf(gyn, 32.f, 31.5f);
        const float x0f = floorf(gx), y0f = floorf(gy);
        const float wx1 = gx - x0f, wx0 = 1.f - wx1;
        const float wy1 = gy - y0f, wy0 = 1.f - wy1;
        const int ix = (int)x0f, iy = (int)y0f;
        const bool vx0 = (ix >= 0) && (ix < 64);
        const bool vx1 = (ix >= -1) && (ix < 63);
        const bool vy0 = (iy >= 0) && (iy < 64);
        const bool vy1 = (iy >= -1) && (iy < 63);
        const int cx0 = min(max(ix, 0), 63);
        const int cx1 = min(max(ix + 1, 0), 63);
        const int cy0 = min(max(iy, 0), 63);
        const int cy1 = min(max(iy + 1, 0), 63);
        const float w00 = wx0 * wy0 * ((vx0 && vy0) ? 1.f : 0.f);
        const float w10 = wx1 * wy0 * ((vx1 && vy0) ? 1.f : 0.f);
        const float w01 = wx0 * wy1 * ((vx0 && vy1) ? 1.f : 0.f);
        const float w11 = wx1 * wy1 * ((vx1 && vy1) ? 1.f : 0.f);
        const int r0 = cy0 * 64, r1 = cy1 * 64;
#pragma unroll
        for (int i = 0; i < 8; ++i) {
            const int c = c0 + 4 * i;
            const float* img = x + (((size_t)b * 32 + c) << 12);
            const float v = w00 * img[r0 + cx0] + w10 * img[r0 + cx1]
                          + w01 * img[r1 + cx0] + w11 * img[r1 + cx1];
            __builtin_nontemporal_store(v, &out[(((size_t)b * 32 + c) << 12) + h * 64 + w]);
        }
    }
}

// ===================== kernels =====================
__global__ __launch_bounds__(256, 4) void st_coop(const float* __restrict__ x,
                                                  const float* __restrict__ w1,
                                                  const float* __restrict__ b1,
                                                  const float* __restrict__ w2,
                                                  const float* __restrict__ b2,
                                                  const float* __restrict__ w3,
                                                  const float* __restrict__ b3,
                                                  float* __restrict__ out,
                                                  float* __restrict__ ws) {
    cg::grid_group grid = cg::this_grid();
    __shared__ __align__(16) char smem[32768];
    float* partial = ws;
    float* theta   = ws + (size_t)256 * STRB;

    phase1(blockIdx.x, x, w1, partial, smem);
    grid.sync();
    if (blockIdx.x < 256)
        phase2(blockIdx.x, partial, b1, w2, b2, w3, b3, theta, smem);
    grid.sync();
    phase3(blockIdx.x, x, theta, out);
}

__global__ __launch_bounds__(256) void st_p1k(const float* __restrict__ x,
                                              const float* __restrict__ w1,
                                              float* __restrict__ partial) {
    __shared__ __align__(16) char smem[32768];
    phase1(blockIdx.x, x, w1, partial, smem);
}

__global__ __launch_bounds__(256) void st_p2k(const float* __restrict__ partial,
                                              const float* __restrict__ b1,
                                              const float* __restrict__ w2,
                                              const float* __restrict__ b2,
                                              const float* __restrict__ w3,
                                              const float* __restrict__ b3,
                                              float* __restrict__ theta) {
    __shared__ __align__(16) char smem[4352];
    phase2(blockIdx.x, partial, b1, w2, b2, w3, b3, theta, smem);
}

__global__ __launch_bounds__(256) void st_p3k(const float* __restrict__ x,
                                              const float* __restrict__ theta,
                                              float* __restrict__ out) {
    phase3(blockIdx.x, x, theta, out);
}

extern "C" void kernel_launch(void* const* d_in, const int* in_sizes, int n_in,
                              void* d_out, int out_size, void* d_ws, size_t ws_size,
                              hipStream_t stream) {
    const float* x  = (const float*)d_in[0];
    const float* w1 = (const float*)d_in[1];
    const float* b1 = (const float*)d_in[2];
    const float* w2 = (const float*)d_in[3];
    const float* b2 = (const float*)d_in[4];
    const float* w3 = (const float*)d_in[5];
    const float* b3 = (const float*)d_in[6];
    float* out = (float*)d_out;
    float* ws  = (float*)d_ws;                       // partial 33.5 MB + theta 2 KB
    float* partial = ws;
    float* theta   = ws + (size_t)256 * STRB;

    // Deterministic cooperative-capability gate (host-side queries only; no alloc/sync).
    bool launched = false;
    if (ws_size >= ((size_t)256 * STRB + 2048) * sizeof(float)) {
        int ncu = 0, nblk = 0, dev = 0;
        (void)hipGetDevice(&dev);
        (void)hipDeviceGetAttribute(&ncu, hipDeviceAttributeMultiprocessorCount, dev);
        (void)hipOccupancyMaxActiveBlocksPerMultiprocessor(&nblk, st_coop, 256, 0);
        if (ncu > 0 && nblk > 0 && (long long)nblk * ncu >= 1024) {
            void* args[] = {(void*)&x, (void*)&w1, (void*)&b1, (void*)&w2, (void*)&b2,
                            (void*)&w3, (void*)&b3, (void*)&out, (void*)&ws};
            launched = (hipLaunchCooperativeKernel((void*)st_coop, dim3(1024), dim3(256),
                                                   args, 0, stream) == hipSuccess);
        }
    }
    if (!launched) {
        st_p1k<<<1024, 256, 0, stream>>>(x, w1, partial);
        st_p2k<<<256, 256, 0, stream>>>(partial, b1, w2, b2, w3, b3, theta);
        st_p3k<<<1024, 256, 0, stream>>>(x, theta, out);
    }
}